// Round 11
// baseline (1320.948 us; speedup 1.0000x reference)
//
#include <hip/hip_runtime.h>

#define N_NODES 100000
#define N_EDGES 1600000
#define D 128
#define RPB 64                        // node rows per bucket
#define NBUCKET 1563                  // ceil(N_NODES / RPB)
#define NBLK 196                      // edge chunks
#define EPB 8192                      // edges per chunk
#define AGG_CAP 2048                  // max edges per bucket (power of 2 for masking)
#define XCB 3125                      // xconv blocks (12.8M floats / 4096)
#define SCAN_PAD 1792                 // 256*7 >= NBUCKET

constexpr float LN_EPS   = 1e-5f;
constexpr float MEAN_EPS = 1e-8f;

typedef __attribute__((ext_vector_type(8))) short bf16x8;
typedef __attribute__((ext_vector_type(4))) float f32x4;
typedef __attribute__((ext_vector_type(2))) float f32x2;
typedef __attribute__((ext_vector_type(4))) unsigned uint4e;
typedef __attribute__((ext_vector_type(2))) unsigned uint2e;

__device__ inline unsigned short f2bf(float f) {
  union { float f; unsigned u; } v; v.f = f;
  return (unsigned short)((v.u + 0x7FFFu + ((v.u >> 16) & 1u)) >> 16);
}
__device__ inline unsigned pack2(float a, float b) {
  return (unsigned)f2bf(a) | ((unsigned)f2bf(b) << 16);
}

// ---------------------------------------------------------------------------
// Fused prep: [0,NBLK) per-chunk bucket sort (hist -> scan -> LDS scatter ->
// dense write + packed transposed chunkoff). [NBLK,NBLK+XCB): x -> fp8-e4m3
// x8 (128 B/row gather table). Last 16 = W concat + bias + x8 zero-pad row.
// (unchanged from R9)
// ---------------------------------------------------------------------------
__global__ __launch_bounds__(256) void prep_sort(
    const float* __restrict__ x, const int* __restrict__ ei,
    const float* __restrict__ Wself, const float* __restrict__ Wagg,
    const float* __restrict__ bself, const float* __restrict__ bagg,
    unsigned char* __restrict__ x8,
    unsigned short* __restrict__ wcat, float* __restrict__ bsum,
    unsigned* __restrict__ ent_sorted, int* __restrict__ chunkoff) {
  __shared__ int ent_s[EPB];        // 32 KB
  __shared__ int cnt_s[SCAN_PAD];   // 7 KB
  __shared__ int off_s[SCAN_PAD];   // 7 KB (becomes cursors after chunkoff write)
  __shared__ int sb[256];
  const int bid = blockIdx.x;
  const int t = threadIdx.x;

  if (bid < NBLK) {
    const int ebase = bid * EPB;
    const int nch = min(EPB, N_EDGES - ebase);       // last chunk: 2560
    const int base4 = bid * (EPB / 4);
    const int end4 = base4 + (nch >> 2);             // nch divisible by 4

    for (int i = t; i < SCAN_PAD; i += 256) cnt_s[i] = 0;
    __syncthreads();

    // pass 1: histogram
#pragma unroll
    for (int k = 0; k < EPB / 1024; ++k) {
      int i4 = base4 + k * 256 + t;
      if (i4 < end4) {
        int4 r = ((const int4*)ei)[i4];
        atomicAdd(&cnt_s[r.x >> 6], 1);
        atomicAdd(&cnt_s[r.y >> 6], 1);
        atomicAdd(&cnt_s[r.z >> 6], 1);
        atomicAdd(&cnt_s[r.w >> 6], 1);
      }
    }
    __syncthreads();

    // blocked exclusive scan over SCAN_PAD (=256*7) entries
    int psum = 0;
#pragma unroll
    for (int i = 0; i < 7; ++i) psum += cnt_s[t * 7 + i];
    sb[t] = psum;
    __syncthreads();
    for (int off = 1; off < 256; off <<= 1) {
      int u = (t >= off) ? sb[t - off] : 0;
      __syncthreads();
      sb[t] += u;
      __syncthreads();
    }
    int run = sb[t] - psum;
#pragma unroll
    for (int i = 0; i < 7; ++i) {
      off_s[t * 7 + i] = run;
      run += cnt_s[t * 7 + i];
    }
    __syncthreads();

    // packed transposed chunkoff: chunkoff[b*NBLK + chunk] = beg | (len<<14)
    for (int b = t; b < NBUCKET; b += 256)
      chunkoff[b * NBLK + bid] = off_s[b] | (cnt_s[b] << 14);
    __syncthreads();

    // pass 2: LDS scatter into bucket-sorted order (off_s as cursors)
#pragma unroll
    for (int k = 0; k < EPB / 1024; ++k) {
      int i4 = base4 + k * 256 + t;
      if (i4 < end4) {
        int4 r = ((const int4*)ei)[i4];
        int4 c = ((const int4*)(ei + N_EDGES))[i4];
        int p0 = atomicAdd(&off_s[r.x >> 6], 1);
        ent_s[p0] = ((r.x & 63) << 17) | c.x;
        int p1 = atomicAdd(&off_s[r.y >> 6], 1);
        ent_s[p1] = ((r.y & 63) << 17) | c.y;
        int p2 = atomicAdd(&off_s[r.z >> 6], 1);
        ent_s[p2] = ((r.z & 63) << 17) | c.z;
        int p3 = atomicAdd(&off_s[r.w >> 6], 1);
        ent_s[p3] = ((r.w & 63) << 17) | c.w;
      }
    }
    __syncthreads();

    // dense coalesced write-out
    for (int i = t; i < nch; i += 256)
      ent_sorted[ebase + i] = (unsigned)ent_s[i];
  } else if (bid < NBLK + XCB) {
    // ---- xconv: thread t converts 16 consecutive floats -> 16 B fp8 (x8).
    const int f = (bid - NBLK) * 4096 + t * 16;      // flat float index
    const float4 v0 = ((const float4*)x)[(f >> 2) + 0];
    const float4 v1 = ((const float4*)x)[(f >> 2) + 1];
    const float4 v2 = ((const float4*)x)[(f >> 2) + 2];
    const float4 v3 = ((const float4*)x)[(f >> 2) + 3];
    unsigned q0 = 0, q1 = 0, q2 = 0, q3 = 0;
    q0 = __builtin_amdgcn_cvt_pk_fp8_f32(v0.x, v0.y, q0, false);
    q0 = __builtin_amdgcn_cvt_pk_fp8_f32(v0.z, v0.w, q0, true);
    q1 = __builtin_amdgcn_cvt_pk_fp8_f32(v1.x, v1.y, q1, false);
    q1 = __builtin_amdgcn_cvt_pk_fp8_f32(v1.z, v1.w, q1, true);
    q2 = __builtin_amdgcn_cvt_pk_fp8_f32(v2.x, v2.y, q2, false);
    q2 = __builtin_amdgcn_cvt_pk_fp8_f32(v2.z, v2.w, q2, true);
    q3 = __builtin_amdgcn_cvt_pk_fp8_f32(v3.x, v3.y, q3, false);
    q3 = __builtin_amdgcn_cvt_pk_fp8_f32(v3.z, v3.w, q3, true);
    uint4e q; q.x = q0; q.y = q1; q.z = q2; q.w = q3;
    *(uint4e*)(x8 + f) = q;
  } else {
    // ---- wconv: 16 blocks cover 128x256 weights; blk0 also bias + pad row
    const int blk = bid - NBLK - XCB;
#pragma unroll
    for (int k = 0; k < 8; ++k) {
      int idx = blk * 2048 + k * 256 + t;
      int o = idx >> 8, kc = idx & 255;
      float v = (kc < 128) ? Wself[o * 128 + kc] : Wagg[o * 128 + (kc - 128)];
      wcat[o * 256 + kc] = f2bf(v);
    }
    if (blk == 0 && t < 128) bsum[t] = bself[t] + bagg[t];
    if (blk == 0 && t < 32)   // zero pad row (col == N_NODES redirect target)
      *(unsigned*)(x8 + (size_t)N_NODES * 128 + t * 4) = 0u;
  }
}

// ---------------------------------------------------------------------------
// Aggregate v5 (fixed): NO counting sort, NO rounds, NO shfl reductions.
// Stage the bucket's entries (unsorted), then stream edges densely: each
// lane loads 4 fp8 cols of an edge row, cvt_pk to f32, ds_add_f32 into a
// swizzled 64x128 LDS accumulator. swz(c)=(c&3)*32+(c>>2): lane lq's j-th
// add hits bank lq -> 2 lanes/bank (free). Output fix vs R10: out row
// stride is 128 unsigneds (512 B), mean occupies the first 64.
// ---------------------------------------------------------------------------
__global__ __launch_bounds__(512) void aggregate(
    const unsigned char* __restrict__ x8, const unsigned* __restrict__ ent_sorted,
    const int* __restrict__ chunkoff, float* out) {
  __shared__ float acc_s[RPB * 128];    // 32 KB, swizzled cols
  __shared__ int ent_s[AGG_CAP];        // 8 KB
  __shared__ int cnt_s[RPB];
  __shared__ int wsum[4];

  const int b = blockIdx.x;
  const int t = threadIdx.x;
  const int w = t >> 6, lane = t & 63;

  // zero accumulator + counts
  for (int i = t; i < RPB * 128 / 4; i += 512)
    ((f32x4*)acc_s)[i] = (f32x4)(0.0f);
  if (t < RPB) cnt_s[t] = 0;

  // packed slice info + shfl inclusive scan over waves 0-3 (t < 256)
  int beg = 0, len = 0;
  if (t < NBLK) {
    int pk = chunkoff[b * NBLK + t];
    beg = pk & 16383;
    len = pk >> 14;
  }
  int v = len;
#pragma unroll
  for (int off = 1; off < 64; off <<= 1) {
    int u = __shfl_up(v, off, 64);
    if (lane >= off) v += u;
  }
  if (w < 4 && lane == 63) wsum[w] = v;
  __syncthreads();
  int n = wsum[0] + wsum[1] + wsum[2] + wsum[3];
  if (n > AGG_CAP) n = AGG_CAP;
  if (t < NBLK) {
    int pre = 0;
    for (int i = 0; i < w; ++i) pre += wsum[i];
    int dst = pre + v - len;               // exclusive position
    const unsigned* src = ent_sorted + t * EPB + beg;
    for (int i = 0; i < len; ++i)
      if (dst + i < AGG_CAP) ent_s[dst + i] = (int)src[i];
  }
  __syncthreads();

  // degree histogram (int atomics, ~2 per thread)
  for (int i = t; i < n; i += 512) atomicAdd(&cnt_s[(ent_s[i] >> 17) & 63], 1);

  // streaming scatter-accumulate: wave processes 4 edges/iter (2 per load,
  // half = lane>>5 selects the edge; lane lq covers fp8 cols 4lq..4lq+3).
  const int half = lane >> 5, lq = lane & 31;
  for (int i = w * 4; i < n; i += 32) {
    int idx0 = i + half;
    int idx1 = i + 2 + half;
    int e0 = ent_s[idx0 & (AGG_CAP - 1)];
    int e1 = ent_s[idx1 & (AGG_CAP - 1)];
    int r0 = (e0 >> 17) & 63, c0 = e0 & 0x1FFFF;
    int r1 = (e1 >> 17) & 63, c1 = e1 & 0x1FFFF;
    if (idx0 >= n) { r0 = 0; c0 = N_NODES; }        // zero row -> adds 0
    if (idx1 >= n) { r1 = 0; c1 = N_NODES; }
    unsigned p0 = *(const unsigned*)(x8 + (size_t)c0 * 128 + lq * 4);
    unsigned p1 = *(const unsigned*)(x8 + (size_t)c1 * 128 + lq * 4);
    f32x2 l0 = __builtin_amdgcn_cvt_pk_f32_fp8(p0, false);
    f32x2 h0 = __builtin_amdgcn_cvt_pk_f32_fp8(p0, true);
    float* a0 = &acc_s[r0 * 128 + lq];
    atomicAdd(a0 +  0, l0.x);                        // col 4lq   -> swz j=0
    atomicAdd(a0 + 32, l0.y);                        // col 4lq+1 -> swz j=1
    atomicAdd(a0 + 64, h0.x);
    atomicAdd(a0 + 96, h0.y);
    f32x2 l1 = __builtin_amdgcn_cvt_pk_f32_fp8(p1, false);
    f32x2 h1 = __builtin_amdgcn_cvt_pk_f32_fp8(p1, true);
    float* a1 = &acc_s[r1 * 128 + lq];
    atomicAdd(a1 +  0, l1.x);
    atomicAdd(a1 + 32, l1.y);
    atomicAdd(a1 + 64, h1.x);
    atomicAdd(a1 + 96, h1.y);
  }
  __syncthreads();

  // output: mean (un-swizzle), bf16-packed into first 256 B of out row.
  // out row stride = 128 floats = 128 unsigneds.
  const int nodebase = b << 6;
  for (int idx = t; idx < RPB * 64; idx += 512) {
    int r = idx >> 6, d = idx & 63;
    int node = nodebase + r;
    if (node < N_NODES) {
      float inv = 1.0f / ((float)cnt_s[r] + MEAN_EPS);
      int ca = 2 * d, cb = 2 * d + 1;
      float va = acc_s[r * 128 + (ca & 3) * 32 + (ca >> 2)];
      float vb = acc_s[r * 128 + (cb & 3) * 32 + (cb >> 2)];
      ((unsigned*)out)[(size_t)node * 128 + d] = pack2(va * inv, vb * inv);
    }
  }
}

// ---------------------------------------------------------------------------
// MFMA GEMM: C[100000x128] = [x | mean_bf16] (K=256) @ Wcat^T + ReLU + LN
// v2b: B-only LDS (67.6 KB -> 2 blocks/CU); A x-half from fp32 x converted
// in-register; mean half read bf16 from out. In-register LN epilogue.
// (unchanged from R9)
// ---------------------------------------------------------------------------
__global__ __launch_bounds__(512, 4) void gemm_mfma_ln(
    const float* __restrict__ x, const float* out_mean,
    const unsigned short* __restrict__ wcat, const float* __restrict__ bsum,
    const float* __restrict__ gamma, const float* __restrict__ beta,
    float* out) {
  __shared__ unsigned short Bs[128 * 264];   // 67.6 KB
  __shared__ float bias_s[128];

  const int t = threadIdx.x;
  const int w = t >> 6, lane = t & 63;
  const int q = lane >> 4, s = lane & 15;
  const int base = blockIdx.x * 128;

  if (t < 128) bias_s[t] = bsum[t];

#pragma unroll
  for (int r = 0; r < 8; ++r) {
    int f = r * 512 + t;
    int row = f >> 5, c = f & 31;
    uint4 v = *(const uint4*)(wcat + row * 256 + c * 8);
    *(uint4*)(Bs + row * 264 + c * 8) = v;
  }

  const int arow = base + w * 16 + s;
  const int asafe = (arow < N_NODES) ? arow : 0;
  const float* xrow = x + (size_t)asafe * 128;
  const unsigned short* mrow = (const unsigned short*)(out_mean + (size_t)asafe * 128);
  bf16x8 a[8];
#pragma unroll
  for (int kk = 0; kk < 4; ++kk) {
    const float4 f0 = *(const float4*)(xrow + kk * 32 + q * 8);
    const float4 f1 = *(const float4*)(xrow + kk * 32 + q * 8 + 4);
    bf16x8 av;
    av[0] = (short)f2bf(f0.x); av[1] = (short)f2bf(f0.y);
    av[2] = (short)f2bf(f0.z); av[3] = (short)f2bf(f0.w);
    av[4] = (short)f2bf(f1.x); av[5] = (short)f2bf(f1.y);
    av[6] = (short)f2bf(f1.z); av[7] = (short)f2bf(f1.w);
    a[kk] = av;
  }
#pragma unroll
  for (int kk = 0; kk < 4; ++kk)
    a[4 + kk] = *(const bf16x8*)(mrow + kk * 32 + q * 8);

  __syncthreads();

  f32x4 acc[8];
#pragma unroll
  for (int j = 0; j < 8; ++j) acc[j] = (f32x4)(0.0f);

#pragma unroll
  for (int kk = 0; kk < 8; ++kk) {
    const int ko = kk * 32 + q * 8;
#pragma unroll
    for (int j = 0; j < 8; ++j) {
      bf16x8 bv = *(const bf16x8*)(Bs + (j * 16 + s) * 264 + ko);
      acc[j] = __builtin_amdgcn_mfma_f32_16x16x32_bf16(a[kk], bv, acc[j], 0, 0, 0);
    }
  }

#pragma unroll
  for (int j = 0; j < 8; ++j) {
    float bb = bias_s[j * 16 + s];
#pragma unroll
    for (int r = 0; r < 4; ++r)
      acc[j][r] = fmaxf(acc[j][r] + bb, 0.0f);
  }

  float g[8], be[8];
#pragma unroll
  for (int j = 0; j < 8; ++j) {
    g[j]  = gamma[j * 16 + s];
    be[j] = beta[j * 16 + s];
  }

#pragma unroll
  for (int r = 0; r < 4; ++r) {
    float s1 = 0.f, s2 = 0.f;
#pragma unroll
    for (int j = 0; j < 8; ++j) {
      float h = acc[j][r];
      s1 += h; s2 += h * h;
    }
#pragma unroll
    for (int m = 1; m < 16; m <<= 1) {
      s1 += __shfl_xor(s1, m, 64);
      s2 += __shfl_xor(s2, m, 64);
    }
    int node = base + w * 16 + q * 4 + r;
    if (node < N_NODES) {
      float mu = s1 * (1.0f / 128.0f);
      float var = s2 * (1.0f / 128.0f) - mu * mu;
      float rstd = rsqrtf(var + LN_EPS);
      float* orow = out + (size_t)node * 128;
#pragma unroll
      for (int j = 0; j < 8; ++j)
        orow[j * 16 + s] = (acc[j][r] - mu) * rstd * g[j] + be[j];
    }
  }
}

extern "C" void kernel_launch(void* const* d_in, const int* in_sizes, int n_in,
                              void* d_out, int out_size, void* d_ws, size_t ws_size,
                              hipStream_t stream) {
  const float* x     = (const float*)d_in[0];
  const int*   ei    = (const int*)d_in[1];
  const float* Wagg  = (const float*)d_in[2];
  const float* bagg  = (const float*)d_in[3];
  const float* Wself = (const float*)d_in[4];
  const float* bself = (const float*)d_in[5];
  const float* gamma = (const float*)d_in[6];
  const float* beta  = (const float*)d_in[7];
  float* out = (float*)d_out;

  // ws: x8 | wcat | bsum | ent_sorted | chunkoff  (~21 MB)
  unsigned char*  x8   = (unsigned char*)d_ws;                  // 12.8 MB fp8 (+pad row)
  unsigned short* wcat = (unsigned short*)(x8 + (size_t)(N_NODES + 1) * D); // 64 KB
  float* bsum      = (float*)(wcat + 128 * 256);                // 512 B
  unsigned* ent_sorted = (unsigned*)(bsum + 128);               // NBLK*EPB u32 (6.4 MB)
  int* chunkoff    = (int*)(ent_sorted + (size_t)NBLK * EPB);   // NBUCKET*NBLK (1.2 MB)

  prep_sort<<<NBLK + XCB + 16, 256, 0, stream>>>(
      x, ei, Wself, Wagg, bself, bagg, x8, wcat, bsum, ent_sorted, chunkoff);

  aggregate<<<NBUCKET, 512, 0, stream>>>(x8, ent_sorted, chunkoff, out);

  gemm_mfma_ln<<<(N_NODES + 127) / 128, 512, 0, stream>>>(
      x, out, wcat, bsum, gamma, beta, out);
}

// Round 12
// 1318.869 us; speedup vs baseline: 1.0016x; 1.0016x over previous
//
#include <hip/hip_runtime.h>

#define N_NODES 100000
#define N_EDGES 1600000
#define D 128
#define RPB 64                        // node rows per bucket
#define NBUCKET 1563                  // ceil(N_NODES / RPB)
#define NBLK 196                      // edge chunks
#define EPB 8192                      // edges per chunk
#define AGG_CAP 2048                  // max edges per bucket (power of 2 for masking)
#define XCB 3125                      // xconv blocks (12.8M floats / 4096)
#define SCAN_PAD 1792                 // 256*7 >= NBUCKET

constexpr float LN_EPS   = 1e-5f;
constexpr float MEAN_EPS = 1e-8f;

typedef __attribute__((ext_vector_type(8))) short bf16x8;
typedef __attribute__((ext_vector_type(4))) float f32x4;
typedef __attribute__((ext_vector_type(2))) float f32x2;
typedef __attribute__((ext_vector_type(4))) unsigned uint4e;
typedef __attribute__((ext_vector_type(2))) unsigned uint2e;

__device__ inline unsigned short f2bf(float f) {
  union { float f; unsigned u; } v; v.f = f;
  return (unsigned short)((v.u + 0x7FFFu + ((v.u >> 16) & 1u)) >> 16);
}
__device__ inline unsigned pack2(float a, float b) {
  return (unsigned)f2bf(a) | ((unsigned)f2bf(b) << 16);
}

// hardware LDS float atomic (fire-and-forget). HIP's atomicAdd on shared
// floats lowers to a CAS loop without -munsafe-fp-atomics (R11: 19x slow);
// emit ds_add_f32 directly. 4 adds share one address via offset: immediates
// (cols swizzled 128 B apart).
__device__ inline void lds_fadd4(unsigned a, float x, float y, float z, float w) {
  asm volatile("ds_add_f32 %0, %1 offset:0\n\t"
               "ds_add_f32 %0, %2 offset:128\n\t"
               "ds_add_f32 %0, %3 offset:256\n\t"
               "ds_add_f32 %0, %4 offset:384"
               :: "v"(a), "v"(x), "v"(y), "v"(z), "v"(w) : "memory");
}

// ---------------------------------------------------------------------------
// Fused prep: [0,NBLK) per-chunk bucket sort (hist -> scan -> LDS scatter ->
// dense write + packed transposed chunkoff). [NBLK,NBLK+XCB): x -> fp8-e4m3
// x8 (128 B/row gather table). Last 16 = W concat + bias + x8 zero-pad row.
// (unchanged from R9)
// ---------------------------------------------------------------------------
__global__ __launch_bounds__(256) void prep_sort(
    const float* __restrict__ x, const int* __restrict__ ei,
    const float* __restrict__ Wself, const float* __restrict__ Wagg,
    const float* __restrict__ bself, const float* __restrict__ bagg,
    unsigned char* __restrict__ x8,
    unsigned short* __restrict__ wcat, float* __restrict__ bsum,
    unsigned* __restrict__ ent_sorted, int* __restrict__ chunkoff) {
  __shared__ int ent_s[EPB];        // 32 KB
  __shared__ int cnt_s[SCAN_PAD];   // 7 KB
  __shared__ int off_s[SCAN_PAD];   // 7 KB (becomes cursors after chunkoff write)
  __shared__ int sb[256];
  const int bid = blockIdx.x;
  const int t = threadIdx.x;

  if (bid < NBLK) {
    const int ebase = bid * EPB;
    const int nch = min(EPB, N_EDGES - ebase);       // last chunk: 2560
    const int base4 = bid * (EPB / 4);
    const int end4 = base4 + (nch >> 2);             // nch divisible by 4

    for (int i = t; i < SCAN_PAD; i += 256) cnt_s[i] = 0;
    __syncthreads();

    // pass 1: histogram
#pragma unroll
    for (int k = 0; k < EPB / 1024; ++k) {
      int i4 = base4 + k * 256 + t;
      if (i4 < end4) {
        int4 r = ((const int4*)ei)[i4];
        atomicAdd(&cnt_s[r.x >> 6], 1);
        atomicAdd(&cnt_s[r.y >> 6], 1);
        atomicAdd(&cnt_s[r.z >> 6], 1);
        atomicAdd(&cnt_s[r.w >> 6], 1);
      }
    }
    __syncthreads();

    // blocked exclusive scan over SCAN_PAD (=256*7) entries
    int psum = 0;
#pragma unroll
    for (int i = 0; i < 7; ++i) psum += cnt_s[t * 7 + i];
    sb[t] = psum;
    __syncthreads();
    for (int off = 1; off < 256; off <<= 1) {
      int u = (t >= off) ? sb[t - off] : 0;
      __syncthreads();
      sb[t] += u;
      __syncthreads();
    }
    int run = sb[t] - psum;
#pragma unroll
    for (int i = 0; i < 7; ++i) {
      off_s[t * 7 + i] = run;
      run += cnt_s[t * 7 + i];
    }
    __syncthreads();

    // packed transposed chunkoff: chunkoff[b*NBLK + chunk] = beg | (len<<14)
    for (int b = t; b < NBUCKET; b += 256)
      chunkoff[b * NBLK + bid] = off_s[b] | (cnt_s[b] << 14);
    __syncthreads();

    // pass 2: LDS scatter into bucket-sorted order (off_s as cursors)
#pragma unroll
    for (int k = 0; k < EPB / 1024; ++k) {
      int i4 = base4 + k * 256 + t;
      if (i4 < end4) {
        int4 r = ((const int4*)ei)[i4];
        int4 c = ((const int4*)(ei + N_EDGES))[i4];
        int p0 = atomicAdd(&off_s[r.x >> 6], 1);
        ent_s[p0] = ((r.x & 63) << 17) | c.x;
        int p1 = atomicAdd(&off_s[r.y >> 6], 1);
        ent_s[p1] = ((r.y & 63) << 17) | c.y;
        int p2 = atomicAdd(&off_s[r.z >> 6], 1);
        ent_s[p2] = ((r.z & 63) << 17) | c.z;
        int p3 = atomicAdd(&off_s[r.w >> 6], 1);
        ent_s[p3] = ((r.w & 63) << 17) | c.w;
      }
    }
    __syncthreads();

    // dense coalesced write-out
    for (int i = t; i < nch; i += 256)
      ent_sorted[ebase + i] = (unsigned)ent_s[i];
  } else if (bid < NBLK + XCB) {
    // ---- xconv: thread t converts 16 consecutive floats -> 16 B fp8 (x8).
    const int f = (bid - NBLK) * 4096 + t * 16;      // flat float index
    const float4 v0 = ((const float4*)x)[(f >> 2) + 0];
    const float4 v1 = ((const float4*)x)[(f >> 2) + 1];
    const float4 v2 = ((const float4*)x)[(f >> 2) + 2];
    const float4 v3 = ((const float4*)x)[(f >> 2) + 3];
    unsigned q0 = 0, q1 = 0, q2 = 0, q3 = 0;
    q0 = __builtin_amdgcn_cvt_pk_fp8_f32(v0.x, v0.y, q0, false);
    q0 = __builtin_amdgcn_cvt_pk_fp8_f32(v0.z, v0.w, q0, true);
    q1 = __builtin_amdgcn_cvt_pk_fp8_f32(v1.x, v1.y, q1, false);
    q1 = __builtin_amdgcn_cvt_pk_fp8_f32(v1.z, v1.w, q1, true);
    q2 = __builtin_amdgcn_cvt_pk_fp8_f32(v2.x, v2.y, q2, false);
    q2 = __builtin_amdgcn_cvt_pk_fp8_f32(v2.z, v2.w, q2, true);
    q3 = __builtin_amdgcn_cvt_pk_fp8_f32(v3.x, v3.y, q3, false);
    q3 = __builtin_amdgcn_cvt_pk_fp8_f32(v3.z, v3.w, q3, true);
    uint4e q; q.x = q0; q.y = q1; q.z = q2; q.w = q3;
    *(uint4e*)(x8 + f) = q;
  } else {
    // ---- wconv: 16 blocks cover 128x256 weights; blk0 also bias + pad row
    const int blk = bid - NBLK - XCB;
#pragma unroll
    for (int k = 0; k < 8; ++k) {
      int idx = blk * 2048 + k * 256 + t;
      int o = idx >> 8, kc = idx & 255;
      float v = (kc < 128) ? Wself[o * 128 + kc] : Wagg[o * 128 + (kc - 128)];
      wcat[o * 256 + kc] = f2bf(v);
    }
    if (blk == 0 && t < 128) bsum[t] = bself[t] + bagg[t];
    if (blk == 0 && t < 32)   // zero pad row (col == N_NODES redirect target)
      *(unsigned*)(x8 + (size_t)N_NODES * 128 + t * 4) = 0u;
  }
}

// ---------------------------------------------------------------------------
// Aggregate v5b: scatter-accumulate with REAL ds_add_f32 (inline asm).
// No counting sort, no rounds, no shfl reductions. Stage entries (unsorted),
// stream edges: lane loads 4 fp8 cols of an edge row, cvt_pk to f32,
// ds_add_f32 x4 (shared addr + offset imm) into swizzled 64x128 acc.
// swz(c)=(c&3)*32+(c>>2): lane lq's j-th add hits bank lq -> 2 lanes/bank.
// ---------------------------------------------------------------------------
__global__ __launch_bounds__(512) void aggregate(
    const unsigned char* __restrict__ x8, const unsigned* __restrict__ ent_sorted,
    const int* __restrict__ chunkoff, float* out) {
  __shared__ float acc_s[RPB * 128];    // 32 KB, swizzled cols
  __shared__ int ent_s[AGG_CAP];        // 8 KB
  __shared__ int cnt_s[RPB];
  __shared__ int wsum[4];

  const int b = blockIdx.x;
  const int t = threadIdx.x;
  const int w = t >> 6, lane = t & 63;

  // zero accumulator + counts
  for (int i = t; i < RPB * 128 / 4; i += 512)
    ((f32x4*)acc_s)[i] = (f32x4)(0.0f);
  if (t < RPB) cnt_s[t] = 0;

  // packed slice info + shfl inclusive scan over waves 0-3 (t < 256)
  int beg = 0, len = 0;
  if (t < NBLK) {
    int pk = chunkoff[b * NBLK + t];
    beg = pk & 16383;
    len = pk >> 14;
  }
  int v = len;
#pragma unroll
  for (int off = 1; off < 64; off <<= 1) {
    int u = __shfl_up(v, off, 64);
    if (lane >= off) v += u;
  }
  if (w < 4 && lane == 63) wsum[w] = v;
  __syncthreads();
  int n = wsum[0] + wsum[1] + wsum[2] + wsum[3];
  if (n > AGG_CAP) n = AGG_CAP;
  if (t < NBLK) {
    int pre = 0;
    for (int i = 0; i < w; ++i) pre += wsum[i];
    int dst = pre + v - len;               // exclusive position
    const unsigned* src = ent_sorted + t * EPB + beg;
    for (int i = 0; i < len; ++i)
      if (dst + i < AGG_CAP) ent_s[dst + i] = (int)src[i];
  }
  __syncthreads();

  // degree histogram (int atomics, ~2 per thread)
  for (int i = t; i < n; i += 512) atomicAdd(&cnt_s[(ent_s[i] >> 17) & 63], 1);

  // streaming scatter-accumulate: wave processes 4 edges/iter (2 per load,
  // half = lane>>5 selects the edge; lane lq covers fp8 cols 4lq..4lq+3).
  const int half = lane >> 5, lq = lane & 31;
  const unsigned accb = (unsigned)(unsigned long long)(&acc_s[0]) + lq * 4u;
  for (int i = w * 4; i < n; i += 32) {
    int idx0 = i + half;
    int idx1 = i + 2 + half;
    int e0 = ent_s[idx0 & (AGG_CAP - 1)];
    int e1 = ent_s[idx1 & (AGG_CAP - 1)];
    int r0 = (e0 >> 17) & 63, c0 = e0 & 0x1FFFF;
    int r1 = (e1 >> 17) & 63, c1 = e1 & 0x1FFFF;
    if (idx0 >= n) { r0 = 0; c0 = N_NODES; }        // zero row -> adds 0
    if (idx1 >= n) { r1 = 0; c1 = N_NODES; }
    unsigned p0 = *(const unsigned*)(x8 + (size_t)c0 * 128 + lq * 4);
    unsigned p1 = *(const unsigned*)(x8 + (size_t)c1 * 128 + lq * 4);
    f32x2 l0 = __builtin_amdgcn_cvt_pk_f32_fp8(p0, false);
    f32x2 h0 = __builtin_amdgcn_cvt_pk_f32_fp8(p0, true);
    lds_fadd4(accb + (unsigned)(r0 * 512), l0.x, l0.y, h0.x, h0.y);
    f32x2 l1 = __builtin_amdgcn_cvt_pk_f32_fp8(p1, false);
    f32x2 h1 = __builtin_amdgcn_cvt_pk_f32_fp8(p1, true);
    lds_fadd4(accb + (unsigned)(r1 * 512), l1.x, l1.y, h1.x, h1.y);
  }
  __syncthreads();

  // output: mean (un-swizzle), bf16-packed into first 256 B of out row.
  // out row stride = 128 floats = 128 unsigneds.
  const int nodebase = b << 6;
  for (int idx = t; idx < RPB * 64; idx += 512) {
    int r = idx >> 6, d = idx & 63;
    int node = nodebase + r;
    if (node < N_NODES) {
      float inv = 1.0f / ((float)cnt_s[r] + MEAN_EPS);
      int ca = 2 * d, cb = 2 * d + 1;
      float va = acc_s[r * 128 + (ca & 3) * 32 + (ca >> 2)];
      float vb = acc_s[r * 128 + (cb & 3) * 32 + (cb >> 2)];
      ((unsigned*)out)[(size_t)node * 128 + d] = pack2(va * inv, vb * inv);
    }
  }
}

// ---------------------------------------------------------------------------
// MFMA GEMM: C[100000x128] = [x | mean_bf16] (K=256) @ Wcat^T + ReLU + LN
// v2b: B-only LDS (67.6 KB -> 2 blocks/CU); A x-half from fp32 x converted
// in-register; mean half read bf16 from out. In-register LN epilogue.
// (unchanged from R9)
// ---------------------------------------------------------------------------
__global__ __launch_bounds__(512, 4) void gemm_mfma_ln(
    const float* __restrict__ x, const float* out_mean,
    const unsigned short* __restrict__ wcat, const float* __restrict__ bsum,
    const float* __restrict__ gamma, const float* __restrict__ beta,
    float* out) {
  __shared__ unsigned short Bs[128 * 264];   // 67.6 KB
  __shared__ float bias_s[128];

  const int t = threadIdx.x;
  const int w = t >> 6, lane = t & 63;
  const int q = lane >> 4, s = lane & 15;
  const int base = blockIdx.x * 128;

  if (t < 128) bias_s[t] = bsum[t];

#pragma unroll
  for (int r = 0; r < 8; ++r) {
    int f = r * 512 + t;
    int row = f >> 5, c = f & 31;
    uint4 v = *(const uint4*)(wcat + row * 256 + c * 8);
    *(uint4*)(Bs + row * 264 + c * 8) = v;
  }

  const int arow = base + w * 16 + s;
  const int asafe = (arow < N_NODES) ? arow : 0;
  const float* xrow = x + (size_t)asafe * 128;
  const unsigned short* mrow = (const unsigned short*)(out_mean + (size_t)asafe * 128);
  bf16x8 a[8];
#pragma unroll
  for (int kk = 0; kk < 4; ++kk) {
    const float4 f0 = *(const float4*)(xrow + kk * 32 + q * 8);
    const float4 f1 = *(const float4*)(xrow + kk * 32 + q * 8 + 4);
    bf16x8 av;
    av[0] = (short)f2bf(f0.x); av[1] = (short)f2bf(f0.y);
    av[2] = (short)f2bf(f0.z); av[3] = (short)f2bf(f0.w);
    av[4] = (short)f2bf(f1.x); av[5] = (short)f2bf(f1.y);
    av[6] = (short)f2bf(f1.z); av[7] = (short)f2bf(f1.w);
    a[kk] = av;
  }
#pragma unroll
  for (int kk = 0; kk < 4; ++kk)
    a[4 + kk] = *(const bf16x8*)(mrow + kk * 32 + q * 8);

  __syncthreads();

  f32x4 acc[8];
#pragma unroll
  for (int j = 0; j < 8; ++j) acc[j] = (f32x4)(0.0f);

#pragma unroll
  for (int kk = 0; kk < 8; ++kk) {
    const int ko = kk * 32 + q * 8;
#pragma unroll
    for (int j = 0; j < 8; ++j) {
      bf16x8 bv = *(const bf16x8*)(Bs + (j * 16 + s) * 264 + ko);
      acc[j] = __builtin_amdgcn_mfma_f32_16x16x32_bf16(a[kk], bv, acc[j], 0, 0, 0);
    }
  }

#pragma unroll
  for (int j = 0; j < 8; ++j) {
    float bb = bias_s[j * 16 + s];
#pragma unroll
    for (int r = 0; r < 4; ++r)
      acc[j][r] = fmaxf(acc[j][r] + bb, 0.0f);
  }

  float g[8], be[8];
#pragma unroll
  for (int j = 0; j < 8; ++j) {
    g[j]  = gamma[j * 16 + s];
    be[j] = beta[j * 16 + s];
  }

#pragma unroll
  for (int r = 0; r < 4; ++r) {
    float s1 = 0.f, s2 = 0.f;
#pragma unroll
    for (int j = 0; j < 8; ++j) {
      float h = acc[j][r];
      s1 += h; s2 += h * h;
    }
#pragma unroll
    for (int m = 1; m < 16; m <<= 1) {
      s1 += __shfl_xor(s1, m, 64);
      s2 += __shfl_xor(s2, m, 64);
    }
    int node = base + w * 16 + q * 4 + r;
    if (node < N_NODES) {
      float mu = s1 * (1.0f / 128.0f);
      float var = s2 * (1.0f / 128.0f) - mu * mu;
      float rstd = rsqrtf(var + LN_EPS);
      float* orow = out + (size_t)node * 128;
#pragma unroll
      for (int j = 0; j < 8; ++j)
        orow[j * 16 + s] = (acc[j][r] - mu) * rstd * g[j] + be[j];
    }
  }
}

extern "C" void kernel_launch(void* const* d_in, const int* in_sizes, int n_in,
                              void* d_out, int out_size, void* d_ws, size_t ws_size,
                              hipStream_t stream) {
  const float* x     = (const float*)d_in[0];
  const int*   ei    = (const int*)d_in[1];
  const float* Wagg  = (const float*)d_in[2];
  const float* bagg  = (const float*)d_in[3];
  const float* Wself = (const float*)d_in[4];
  const float* bself = (const float*)d_in[5];
  const float* gamma = (const float*)d_in[6];
  const float* beta  = (const float*)d_in[7];
  float* out = (float*)d_out;

  // ws: x8 | wcat | bsum | ent_sorted | chunkoff  (~21 MB)
  unsigned char*  x8   = (unsigned char*)d_ws;                  // 12.8 MB fp8 (+pad row)
  unsigned short* wcat = (unsigned short*)(x8 + (size_t)(N_NODES + 1) * D); // 64 KB
  float* bsum      = (float*)(wcat + 128 * 256);                // 512 B
  unsigned* ent_sorted = (unsigned*)(bsum + 128);               // NBLK*EPB u32 (6.4 MB)
  int* chunkoff    = (int*)(ent_sorted + (size_t)NBLK * EPB);   // NBUCKET*NBLK (1.2 MB)

  prep_sort<<<NBLK + XCB + 16, 256, 0, stream>>>(
      x, ei, Wself, Wagg, bself, bagg, x8, wcat, bsum, ent_sorted, chunkoff);

  aggregate<<<NBUCKET, 512, 0, stream>>>(x8, ent_sorted, chunkoff, out);

  gemm_mfma_ln<<<(N_NODES + 127) / 128, 512, 0, stream>>>(
      x, out, wcat, bsum, gamma, beta, out);
}

// Round 13
// 196.667 us; speedup vs baseline: 6.7167x; 6.7061x over previous
//
#include <hip/hip_runtime.h>

#define N_NODES 100000
#define N_EDGES 1600000
#define D 128
#define RPB 64                        // node rows per bucket
#define NBUCKET 1563                  // ceil(N_NODES / RPB)
#define NBLK 196                      // edge chunks
#define EPB 8192                      // edges per chunk
#define AGG_CAP 2048                  // max edges per bucket (power of 2 for masking)
#define XCB 3125                      // xconv blocks (12.8M floats / 4096)
#define SCAN_PAD 1792                 // 256*7 >= NBUCKET

constexpr float LN_EPS   = 1e-5f;
constexpr float MEAN_EPS = 1e-8f;

typedef __attribute__((ext_vector_type(8))) short bf16x8;
typedef __attribute__((ext_vector_type(4))) float f32x4;
typedef __attribute__((ext_vector_type(2))) float f32x2;
typedef __attribute__((ext_vector_type(4))) unsigned uint4e;
typedef __attribute__((ext_vector_type(2))) unsigned uint2e;

__device__ inline unsigned short f2bf(float f) {
  union { float f; unsigned u; } v; v.f = f;
  return (unsigned short)((v.u + 0x7FFFu + ((v.u >> 16) & 1u)) >> 16);
}
__device__ inline unsigned pack2(float a, float b) {
  return (unsigned)f2bf(a) | ((unsigned)f2bf(b) << 16);
}

// ---------------------------------------------------------------------------
// Fused prep: [0,NBLK) per-chunk bucket sort (hist -> scan -> LDS scatter ->
// dense write + packed transposed chunkoff). [NBLK,NBLK+XCB): x -> fp8-e4m3
// x8 (128 B/row gather table). Last 16 = W concat + bias + x8 zero-pad row.
// (unchanged from R9)
// ---------------------------------------------------------------------------
__global__ __launch_bounds__(256) void prep_sort(
    const float* __restrict__ x, const int* __restrict__ ei,
    const float* __restrict__ Wself, const float* __restrict__ Wagg,
    const float* __restrict__ bself, const float* __restrict__ bagg,
    unsigned char* __restrict__ x8,
    unsigned short* __restrict__ wcat, float* __restrict__ bsum,
    unsigned* __restrict__ ent_sorted, int* __restrict__ chunkoff) {
  __shared__ int ent_s[EPB];        // 32 KB
  __shared__ int cnt_s[SCAN_PAD];   // 7 KB
  __shared__ int off_s[SCAN_PAD];   // 7 KB (becomes cursors after chunkoff write)
  __shared__ int sb[256];
  const int bid = blockIdx.x;
  const int t = threadIdx.x;

  if (bid < NBLK) {
    const int ebase = bid * EPB;
    const int nch = min(EPB, N_EDGES - ebase);       // last chunk: 2560
    const int base4 = bid * (EPB / 4);
    const int end4 = base4 + (nch >> 2);             // nch divisible by 4

    for (int i = t; i < SCAN_PAD; i += 256) cnt_s[i] = 0;
    __syncthreads();

    // pass 1: histogram
#pragma unroll
    for (int k = 0; k < EPB / 1024; ++k) {
      int i4 = base4 + k * 256 + t;
      if (i4 < end4) {
        int4 r = ((const int4*)ei)[i4];
        atomicAdd(&cnt_s[r.x >> 6], 1);
        atomicAdd(&cnt_s[r.y >> 6], 1);
        atomicAdd(&cnt_s[r.z >> 6], 1);
        atomicAdd(&cnt_s[r.w >> 6], 1);
      }
    }
    __syncthreads();

    // blocked exclusive scan over SCAN_PAD (=256*7) entries
    int psum = 0;
#pragma unroll
    for (int i = 0; i < 7; ++i) psum += cnt_s[t * 7 + i];
    sb[t] = psum;
    __syncthreads();
    for (int off = 1; off < 256; off <<= 1) {
      int u = (t >= off) ? sb[t - off] : 0;
      __syncthreads();
      sb[t] += u;
      __syncthreads();
    }
    int run = sb[t] - psum;
#pragma unroll
    for (int i = 0; i < 7; ++i) {
      off_s[t * 7 + i] = run;
      run += cnt_s[t * 7 + i];
    }
    __syncthreads();

    // packed transposed chunkoff: chunkoff[b*NBLK + chunk] = beg | (len<<14)
    for (int b = t; b < NBUCKET; b += 256)
      chunkoff[b * NBLK + bid] = off_s[b] | (cnt_s[b] << 14);
    __syncthreads();

    // pass 2: LDS scatter into bucket-sorted order (off_s as cursors)
#pragma unroll
    for (int k = 0; k < EPB / 1024; ++k) {
      int i4 = base4 + k * 256 + t;
      if (i4 < end4) {
        int4 r = ((const int4*)ei)[i4];
        int4 c = ((const int4*)(ei + N_EDGES))[i4];
        int p0 = atomicAdd(&off_s[r.x >> 6], 1);
        ent_s[p0] = ((r.x & 63) << 17) | c.x;
        int p1 = atomicAdd(&off_s[r.y >> 6], 1);
        ent_s[p1] = ((r.y & 63) << 17) | c.y;
        int p2 = atomicAdd(&off_s[r.z >> 6], 1);
        ent_s[p2] = ((r.z & 63) << 17) | c.z;
        int p3 = atomicAdd(&off_s[r.w >> 6], 1);
        ent_s[p3] = ((r.w & 63) << 17) | c.w;
      }
    }
    __syncthreads();

    // dense coalesced write-out
    for (int i = t; i < nch; i += 256)
      ent_sorted[ebase + i] = (unsigned)ent_s[i];
  } else if (bid < NBLK + XCB) {
    // ---- xconv: thread t converts 16 consecutive floats -> 16 B fp8 (x8).
    const int f = (bid - NBLK) * 4096 + t * 16;      // flat float index
    const float4 v0 = ((const float4*)x)[(f >> 2) + 0];
    const float4 v1 = ((const float4*)x)[(f >> 2) + 1];
    const float4 v2 = ((const float4*)x)[(f >> 2) + 2];
    const float4 v3 = ((const float4*)x)[(f >> 2) + 3];
    unsigned q0 = 0, q1 = 0, q2 = 0, q3 = 0;
    q0 = __builtin_amdgcn_cvt_pk_fp8_f32(v0.x, v0.y, q0, false);
    q0 = __builtin_amdgcn_cvt_pk_fp8_f32(v0.z, v0.w, q0, true);
    q1 = __builtin_amdgcn_cvt_pk_fp8_f32(v1.x, v1.y, q1, false);
    q1 = __builtin_amdgcn_cvt_pk_fp8_f32(v1.z, v1.w, q1, true);
    q2 = __builtin_amdgcn_cvt_pk_fp8_f32(v2.x, v2.y, q2, false);
    q2 = __builtin_amdgcn_cvt_pk_fp8_f32(v2.z, v2.w, q2, true);
    q3 = __builtin_amdgcn_cvt_pk_fp8_f32(v3.x, v3.y, q3, false);
    q3 = __builtin_amdgcn_cvt_pk_fp8_f32(v3.z, v3.w, q3, true);
    uint4e q; q.x = q0; q.y = q1; q.z = q2; q.w = q3;
    *(uint4e*)(x8 + f) = q;
  } else {
    // ---- wconv: 16 blocks cover 128x256 weights; blk0 also bias + pad row
    const int blk = bid - NBLK - XCB;
#pragma unroll
    for (int k = 0; k < 8; ++k) {
      int idx = blk * 2048 + k * 256 + t;
      int o = idx >> 8, kc = idx & 255;
      float v = (kc < 128) ? Wself[o * 128 + kc] : Wagg[o * 128 + (kc - 128)];
      wcat[o * 256 + kc] = f2bf(v);
    }
    if (blk == 0 && t < 128) bsum[t] = bself[t] + bagg[t];
    if (blk == 0 && t < 32)   // zero pad row (col == N_NODES redirect target)
      *(unsigned*)(x8 + (size_t)N_NODES * 128 + t * 4) = 0u;
  }
}

// ---------------------------------------------------------------------------
// Aggregate v6 = R9 structure (512 threads, counting sort, 4-edge dwordx2
// slots) with inner-loop cuts: (a) f32x2 accumulators -> v_pk_add_f32,
// (b) unmasked full 16-edge rounds + single masked tail round,
// (c) 32-bit voffset addressing (col<<7 against SGPR base).
// ---------------------------------------------------------------------------
__global__ __launch_bounds__(512, 6) void aggregate(
    const unsigned char* __restrict__ x8, const unsigned* __restrict__ ent_sorted,
    const int* __restrict__ chunkoff, float* out) {
  __shared__ int ent_s[AGG_CAP];        // 8 KB
  __shared__ int col_s[AGG_CAP];        // 8 KB (index masked, pads redirected)
  __shared__ int cnt_s[RPB];
  __shared__ int off_s[RPB];
  __shared__ int cur_s[RPB];
  __shared__ int wsum[4];

  const int b = blockIdx.x;
  const int t = threadIdx.x;
  const int w = t >> 6, lane = t & 63;

  // packed slice info + shfl inclusive scan over waves 0-3 (t < 256)
  int beg = 0, len = 0;
  if (t < NBLK) {
    int pk = chunkoff[b * NBLK + t];
    beg = pk & 16383;
    len = pk >> 14;
  }
  int v = len;
#pragma unroll
  for (int off = 1; off < 64; off <<= 1) {
    int u = __shfl_up(v, off, 64);
    if (lane >= off) v += u;
  }
  if (w < 4 && lane == 63) wsum[w] = v;
  if (t < RPB) cnt_s[t] = 0;
  __syncthreads();
  int n = wsum[0] + wsum[1] + wsum[2] + wsum[3];
  if (n > AGG_CAP) n = AGG_CAP;
  if (t < NBLK) {
    int pre = 0;
    for (int i = 0; i < w; ++i) pre += wsum[i];
    int dst = pre + v - len;               // exclusive position
    const unsigned* src = ent_sorted + t * EPB + beg;
    for (int i = 0; i < len; ++i)
      if (dst + i < AGG_CAP) ent_s[dst + i] = (int)src[i];
  }
  __syncthreads();

  // row histogram
  for (int i = t; i < n; i += 512) atomicAdd(&cnt_s[ent_s[i] >> 17], 1);
  __syncthreads();

  // wave 0: shfl scan of 64 row counts -> offsets/cursors
  if (t < RPB) {
    int c = cnt_s[t];
    int sv = c;
#pragma unroll
    for (int off = 1; off < 64; off <<= 1) {
      int u = __shfl_up(sv, off, 64);
      if (t >= off) sv += u;
    }
    off_s[t] = sv - c;
    cur_s[t] = sv - c;
  }
  __syncthreads();

  // scatter into row-sorted order
  for (int i = t; i < n; i += 512) {
    int e = ent_s[i];
    int pos = atomicAdd(&cur_s[e >> 17], 1);
    col_s[pos] = e & 0x1FFFF;
  }
  __syncthreads();

  // gather: wave per row; 4 edges per load slot (e4 = lane>>4), lane covers
  // 8 fp8 cols via dwordx2. 4 loads in flight = 16 edges/round.
  const int e4 = lane >> 4, lq = lane & 15;
  const unsigned co = (unsigned)(lq * 8);
  const int nodebase = b << 6;
  for (int lr = w; lr < RPB; lr += 8) {
    int node = nodebase + lr;
    if (node >= N_NODES) break;
    int rbeg = off_s[lr];
    int deg = cnt_s[lr];
    f32x2 a0 = {0.f, 0.f}, a1 = {0.f, 0.f}, a2 = {0.f, 0.f}, a3 = {0.f, 0.f};
    int j0 = 0;
    // full rounds: no masking, no index wrap needed (indices < rbeg+deg <= n)
    for (; j0 + 16 <= deg; j0 += 16) {
      uint2e p[4];
#pragma unroll
      for (int u = 0; u < 4; ++u) {
        int col = col_s[rbeg + j0 + u * 4 + e4];
        p[u] = *(const uint2e*)(x8 + (((unsigned)col << 7) + co));
      }
#pragma unroll
      for (int u = 0; u < 4; ++u) {
        a0 += __builtin_amdgcn_cvt_pk_f32_fp8(p[u].x, false);
        a1 += __builtin_amdgcn_cvt_pk_f32_fp8(p[u].x, true);
        a2 += __builtin_amdgcn_cvt_pk_f32_fp8(p[u].y, false);
        a3 += __builtin_amdgcn_cvt_pk_f32_fp8(p[u].y, true);
      }
    }
    if (j0 < deg) {
      // single masked tail round (pads redirect to the fp8 zero row)
      uint2e p[4];
#pragma unroll
      for (int u = 0; u < 4; ++u) {
        int idx = j0 + u * 4 + e4;
        int col = col_s[(rbeg + idx) & (AGG_CAP - 1)];
        col = (idx < deg) ? col : N_NODES;
        p[u] = *(const uint2e*)(x8 + (((unsigned)col << 7) + co));
      }
#pragma unroll
      for (int u = 0; u < 4; ++u) {
        a0 += __builtin_amdgcn_cvt_pk_f32_fp8(p[u].x, false);
        a1 += __builtin_amdgcn_cvt_pk_f32_fp8(p[u].x, true);
        a2 += __builtin_amdgcn_cvt_pk_f32_fp8(p[u].y, false);
        a3 += __builtin_amdgcn_cvt_pk_f32_fp8(p[u].y, true);
      }
    }
    // reduce across the 4 edge groups (lanes 16 apart)
    float r0 = a0.x, r1 = a0.y, r2 = a1.x, r3 = a1.y;
    float r4 = a2.x, r5 = a2.y, r6 = a3.x, r7 = a3.y;
    r0 += __shfl_xor(r0, 16, 64); r0 += __shfl_xor(r0, 32, 64);
    r1 += __shfl_xor(r1, 16, 64); r1 += __shfl_xor(r1, 32, 64);
    r2 += __shfl_xor(r2, 16, 64); r2 += __shfl_xor(r2, 32, 64);
    r3 += __shfl_xor(r3, 16, 64); r3 += __shfl_xor(r3, 32, 64);
    r4 += __shfl_xor(r4, 16, 64); r4 += __shfl_xor(r4, 32, 64);
    r5 += __shfl_xor(r5, 16, 64); r5 += __shfl_xor(r5, 32, 64);
    r6 += __shfl_xor(r6, 16, 64); r6 += __shfl_xor(r6, 32, 64);
    r7 += __shfl_xor(r7, 16, 64); r7 += __shfl_xor(r7, 32, 64);
    if (lane < 16) {
      float inv = 1.0f / ((float)deg + MEAN_EPS);
      uint4e o;
      o.x = pack2(r0 * inv, r1 * inv);
      o.y = pack2(r2 * inv, r3 * inv);
      o.z = pack2(r4 * inv, r5 * inv);
      o.w = pack2(r6 * inv, r7 * inv);
      *(uint4e*)((unsigned short*)(out + (size_t)node * D) + lq * 8) = o;
    }
  }
}

// ---------------------------------------------------------------------------
// MFMA GEMM: C[100000x128] = [x | mean_bf16] (K=256) @ Wcat^T + ReLU + LN
// v2b: B-only LDS (67.6 KB -> 2 blocks/CU); A x-half from fp32 x converted
// in-register; mean half read bf16 from out. In-register LN epilogue.
// (unchanged from R9)
// ---------------------------------------------------------------------------
__global__ __launch_bounds__(512, 4) void gemm_mfma_ln(
    const float* __restrict__ x, const float* out_mean,
    const unsigned short* __restrict__ wcat, const float* __restrict__ bsum,
    const float* __restrict__ gamma, const float* __restrict__ beta,
    float* out) {
  __shared__ unsigned short Bs[128 * 264];   // 67.6 KB
  __shared__ float bias_s[128];

  const int t = threadIdx.x;
  const int w = t >> 6, lane = t & 63;
  const int q = lane >> 4, s = lane & 15;
  const int base = blockIdx.x * 128;

  if (t < 128) bias_s[t] = bsum[t];

#pragma unroll
  for (int r = 0; r < 8; ++r) {
    int f = r * 512 + t;
    int row = f >> 5, c = f & 31;
    uint4 v = *(const uint4*)(wcat + row * 256 + c * 8);
    *(uint4*)(Bs + row * 264 + c * 8) = v;
  }

  const int arow = base + w * 16 + s;
  const int asafe = (arow < N_NODES) ? arow : 0;
  const float* xrow = x + (size_t)asafe * 128;
  const unsigned short* mrow = (const unsigned short*)(out_mean + (size_t)asafe * 128);
  bf16x8 a[8];
#pragma unroll
  for (int kk = 0; kk < 4; ++kk) {
    const float4 f0 = *(const float4*)(xrow + kk * 32 + q * 8);
    const float4 f1 = *(const float4*)(xrow + kk * 32 + q * 8 + 4);
    bf16x8 av;
    av[0] = (short)f2bf(f0.x); av[1] = (short)f2bf(f0.y);
    av[2] = (short)f2bf(f0.z); av[3] = (short)f2bf(f0.w);
    av[4] = (short)f2bf(f1.x); av[5] = (short)f2bf(f1.y);
    av[6] = (short)f2bf(f1.z); av[7] = (short)f2bf(f1.w);
    a[kk] = av;
  }
#pragma unroll
  for (int kk = 0; kk < 4; ++kk)
    a[4 + kk] = *(const bf16x8*)(mrow + kk * 32 + q * 8);

  __syncthreads();

  f32x4 acc[8];
#pragma unroll
  for (int j = 0; j < 8; ++j) acc[j] = (f32x4)(0.0f);

#pragma unroll
  for (int kk = 0; kk < 8; ++kk) {
    const int ko = kk * 32 + q * 8;
#pragma unroll
    for (int j = 0; j < 8; ++j) {
      bf16x8 bv = *(const bf16x8*)(Bs + (j * 16 + s) * 264 + ko);
      acc[j] = __builtin_amdgcn_mfma_f32_16x16x32_bf16(a[kk], bv, acc[j], 0, 0, 0);
    }
  }

#pragma unroll
  for (int j = 0; j < 8; ++j) {
    float bb = bias_s[j * 16 + s];
#pragma unroll
    for (int r = 0; r < 4; ++r)
      acc[j][r] = fmaxf(acc[j][r] + bb, 0.0f);
  }

  float g[8], be[8];
#pragma unroll
  for (int j = 0; j < 8; ++j) {
    g[j]  = gamma[j * 16 + s];
    be[j] = beta[j * 16 + s];
  }

#pragma unroll
  for (int r = 0; r < 4; ++r) {
    float s1 = 0.f, s2 = 0.f;
#pragma unroll
    for (int j = 0; j < 8; ++j) {
      float h = acc[j][r];
      s1 += h; s2 += h * h;
    }
#pragma unroll
    for (int m = 1; m < 16; m <<= 1) {
      s1 += __shfl_xor(s1, m, 64);
      s2 += __shfl_xor(s2, m, 64);
    }
    int node = base + w * 16 + q * 4 + r;
    if (node < N_NODES) {
      float mu = s1 * (1.0f / 128.0f);
      float var = s2 * (1.0f / 128.0f) - mu * mu;
      float rstd = rsqrtf(var + LN_EPS);
      float* orow = out + (size_t)node * 128;
#pragma unroll
      for (int j = 0; j < 8; ++j)
        orow[j * 16 + s] = (acc[j][r] - mu) * rstd * g[j] + be[j];
    }
  }
}

extern "C" void kernel_launch(void* const* d_in, const int* in_sizes, int n_in,
                              void* d_out, int out_size, void* d_ws, size_t ws_size,
                              hipStream_t stream) {
  const float* x     = (const float*)d_in[0];
  const int*   ei    = (const int*)d_in[1];
  const float* Wagg  = (const float*)d_in[2];
  const float* bagg  = (const float*)d_in[3];
  const float* Wself = (const float*)d_in[4];
  const float* bself = (const float*)d_in[5];
  const float* gamma = (const float*)d_in[6];
  const float* beta  = (const float*)d_in[7];
  float* out = (float*)d_out;

  // ws: x8 | wcat | bsum | ent_sorted | chunkoff  (~21 MB)
  unsigned char*  x8   = (unsigned char*)d_ws;                  // 12.8 MB fp8 (+pad row)
  unsigned short* wcat = (unsigned short*)(x8 + (size_t)(N_NODES + 1) * D); // 64 KB
  float* bsum      = (float*)(wcat + 128 * 256);                // 512 B
  unsigned* ent_sorted = (unsigned*)(bsum + 128);               // NBLK*EPB u32 (6.4 MB)
  int* chunkoff    = (int*)(ent_sorted + (size_t)NBLK * EPB);   // NBUCKET*NBLK (1.2 MB)

  prep_sort<<<NBLK + XCB + 16, 256, 0, stream>>>(
      x, ei, Wself, Wagg, bself, bagg, x8, wcat, bsum, ent_sorted, chunkoff);

  aggregate<<<NBUCKET, 512, 0, stream>>>(x8, ent_sorted, chunkoff, out);

  gemm_mfma_ln<<<(N_NODES + 127) / 128, 512, 0, stream>>>(
      x, out, wcat, bsum, gamma, beta, out);
}